// Round 7
// baseline (879.922 us; speedup 1.0000x reference)
//
#include <hip/hip_runtime.h>
#include <hip/hip_bf16.h>

#define T_LEN 2048
#define HDIM  64
#define BT    8            // 8 batches/block as TWO independent groups of 4
#define XS    (T_LEN + 4)  // x row stride (floats)
#define HS    72           // h_lds row stride in bf16
#define L2E   1.4426950408889634f   // log2(e)
#define L2E2  2.8853900817779268f   // 2*log2(e)

typedef __attribute__((ext_vector_type(8))) short bf16x8;
typedef __attribute__((ext_vector_type(4))) float f32x4;

__device__ __forceinline__ float rcp_f(float x)  { return __builtin_amdgcn_rcpf(x); }
__device__ __forceinline__ float exp2_f(float x) { return __builtin_amdgcn_exp2f(x); }
__device__ __forceinline__ unsigned short f2bf(float f) {
    unsigned int u = __float_as_uint(f);
    u += 0x7fffu + ((u >> 16) & 1u);
    return (unsigned short)(u >> 16);
}

// One block = 8 batches for all T, split as two independent groups of 4
// (A: b0..b0+3, B: b0+4..b0+7). 256 blocks = 1 block/CU; each wave statically
// interleaves group A's and group B's timestep so B's MFMAs/VALU fill A's
// transcendental+LDS latency (replaces round-6's stochastic 2-block overlap).
// Weights (wf) are shared by both groups; ONE barrier per T-step covers both.
// Lane mapping per group (r5/r6): 16 MFMA cols = 4 batches x 4 row-selects;
// each lane services one (hidden row = hi*4+s, batch) pair per group.
// Zero-quad C: persistent {0,0,0,0} MFMA C-in (D != C), bias added post-select.
__global__ __launch_bounds__(256, 1) void lstm_mfma_kernel(
    const float* __restrict__ x,      // [B, T, 1]
    const float* __restrict__ W_ih,   // [4H, 1]
    const float* __restrict__ W_hh,   // [4H, H]
    const float* __restrict__ b_ih,   // [4H]
    const float* __restrict__ b_hh,   // [4H]
    const float* __restrict__ W_lin,  // [3, H]
    const float* __restrict__ b_lin,  // [3]
    float* __restrict__ out)          // [B, 3]
{
    const int tid  = threadIdx.x;
    const int lane = tid & 63;
    const int wv   = tid >> 6;       // wave 0..3
    const int col  = lane & 15;
    const int hi   = lane >> 4;      // k/row subgroup
    const int bq   = col & 3;        // batch-in-group serviced by this lane
    const int s    = col >> 2;       // C/D reg select: row = hi*4 + s
    const int b0   = blockIdx.x * BT;

    __shared__ float sx[BT][XS];        // full x rows, 8 batches (65.7 KB)
    __shared__ short hl[2][BT][HS];     // double-buffered h (bf16)
    __shared__ float red[BT][3];

    for (int i = tid; i < 2 * BT * HS; i += 256) ((short*)hl)[i] = 0;

    // ---- stage all T for 8 batches (coalesced float4, 16 per thread) ----
    #pragma unroll
    for (int q = 0; q < 16; ++q) {
        const int idx = q * 256 + tid;      // float4 index, 0..4095
        const int row = idx >> 9;           // 512 float4 per batch row
        const int c4  = idx & 511;
        *(float4*)&sx[row][c4 * 4] =
            ((const float4*)(x + (size_t)(b0 + row) * T_LEN))[c4];
    }

    // ---- resident W_hh A-fragments (bf16), prescaled into exp2 domain ----
    const float scl[4] = {L2E, L2E, L2E2, L2E};
    bf16x8 wf[4][2];
    #pragma unroll
    for (int g = 0; g < 4; ++g) {
        const int rowA = 64 * g + 16 * wv + col;
        #pragma unroll
        for (int kc = 0; kc < 2; ++kc) {
            const float* p = W_hh + rowA * HDIM + kc * 32 + hi * 8;
            bf16x8 f;
            #pragma unroll
            for (int j = 0; j < 8; ++j) f[j] = (short)f2bf(p[j] * scl[g]);
            wf[g][kc] = f;
        }
    }
    float wih1[4], bias1[4];   // same hidden row for both groups
    #pragma unroll
    for (int g = 0; g < 4; ++g) {
        const int row = 64 * g + 16 * wv + hi * 4 + s;
        wih1[g]  = W_ih[row] * scl[g];
        bias1[g] = (b_ih[row] + b_hh[row]) * scl[g];
    }

    float cstA = 0.f, hfA = 0.f, cstB = 0.f, hfB = 0.f;
    const int sb0 = s & 1, sb1 = s >> 1;
    const int hwr = 16 * wv + hi * 4 + s;
    const int hi8 = hi * 8;

    const f32x4 zq = {0.f, 0.f, 0.f, 0.f};   // persistent MFMA C-in (never clobbered)

    // static double-buffer pointers
    const short* rdA0 = &hl[0][bq][0];
    const short* rdA1 = &hl[1][bq][0];
    const short* rdB0 = &hl[0][4 + bq][0];
    const short* rdB1 = &hl[1][4 + bq][0];
    short* wrA0 = &hl[0][bq][hwr];
    short* wrA1 = &hl[1][bq][hwr];
    short* wrB0 = &hl[0][4 + bq][hwr];
    short* wrB1 = &hl[1][4 + bq][hwr];
    const float* xpA = &sx[bq][0];
    const float* xpB = &sx[4 + bq][0];

    __syncthreads();   // covers hl zero-init + sx staging

// one group's timestep: pure-matmul MFMA (zero C), select reg s, add tv, nonlin
#define GSTEP(HRD, HWP, XV, CST, HF) do {                                     \
    const bf16x8 hb0 = *(const bf16x8*)((HRD) + hi8);                         \
    const bf16x8 hb1 = *(const bf16x8*)((HRD) + 32 + hi8);                    \
    f32x4 a0 = __builtin_amdgcn_mfma_f32_16x16x32_bf16(wf[0][0], hb0, zq, 0, 0, 0); \
    f32x4 a1 = __builtin_amdgcn_mfma_f32_16x16x32_bf16(wf[1][0], hb0, zq, 0, 0, 0); \
    f32x4 a2 = __builtin_amdgcn_mfma_f32_16x16x32_bf16(wf[2][0], hb0, zq, 0, 0, 0); \
    f32x4 a3 = __builtin_amdgcn_mfma_f32_16x16x32_bf16(wf[3][0], hb0, zq, 0, 0, 0); \
    a0 = __builtin_amdgcn_mfma_f32_16x16x32_bf16(wf[0][1], hb1, a0, 0, 0, 0); \
    a1 = __builtin_amdgcn_mfma_f32_16x16x32_bf16(wf[1][1], hb1, a1, 0, 0, 0); \
    a2 = __builtin_amdgcn_mfma_f32_16x16x32_bf16(wf[2][1], hb1, a2, 0, 0, 0); \
    a3 = __builtin_amdgcn_mfma_f32_16x16x32_bf16(wf[3][1], hb1, a3, 0, 0, 0); \
    const float g0 = (sb1 ? (sb0 ? a0[3] : a0[2]) : (sb0 ? a0[1] : a0[0]))    \
                     + (bias1[0] + wih1[0] * (XV));                           \
    const float g1 = (sb1 ? (sb0 ? a1[3] : a1[2]) : (sb0 ? a1[1] : a1[0]))    \
                     + (bias1[1] + wih1[1] * (XV));                           \
    const float g2 = (sb1 ? (sb0 ? a2[3] : a2[2]) : (sb0 ? a2[1] : a2[0]))    \
                     + (bias1[2] + wih1[2] * (XV));                           \
    const float g3 = (sb1 ? (sb0 ? a3[3] : a3[2]) : (sb0 ? a3[1] : a3[0]))    \
                     + (bias1[3] + wih1[3] * (XV));                           \
    const float iv = rcp_f(1.0f + exp2_f(-g0));                               \
    const float fv = rcp_f(1.0f + exp2_f(-g1));                               \
    const float gv = 1.0f - 2.0f * rcp_f(exp2_f(g2) + 1.0f);                  \
    const float ov = rcp_f(1.0f + exp2_f(-g3));                               \
    (CST) = fv * (CST) + iv * gv;                                             \
    const float th = 1.0f - 2.0f * rcp_f(exp2_f(L2E2 * (CST)) + 1.0f);        \
    (HF) = ov * th;                                                           \
    unsigned int rr;                                                          \
    asm("v_cvt_pk_bf16_f32 %0, %1, %1" : "=v"(rr) : "v"((HF)));               \
    *(HWP) = (short)rr;                                                       \
} while (0)

    for (int t = 0; t < T_LEN; t += 2) {
        const float2 xA = *(const float2*)(xpA + t);   // ds_read_b64
        const float2 xB = *(const float2*)(xpB + t);
        GSTEP(rdA0, wrA1, xA.x, cstA, hfA);            // step t, group A
        GSTEP(rdB0, wrB1, xB.x, cstB, hfB);            // step t, group B
        __syncthreads();
        GSTEP(rdA1, wrA0, xA.y, cstA, hfA);            // step t+1, group A
        GSTEP(rdB1, wrB0, xB.y, cstB, hfB);            // step t+1, group B
        __syncthreads();
    }
#undef GSTEP

    // ---- epilogue: logits = W_lin @ h_T + b_lin, then log_softmax ----
    const float wl0 = W_lin[0 * HDIM + hwr];
    const float wl1 = W_lin[1 * HDIM + hwr];
    const float wl2 = W_lin[2 * HDIM + hwr];
    float pA0 = wl0 * hfA, pA1 = wl1 * hfA, pA2 = wl2 * hfA;
    float pB0 = wl0 * hfB, pB1 = wl1 * hfB, pB2 = wl2 * hfB;
    #pragma unroll
    for (int m = 4; m <= 32; m <<= 1) {
        pA0 += __shfl_xor(pA0, m);  pA1 += __shfl_xor(pA1, m);  pA2 += __shfl_xor(pA2, m);
        pB0 += __shfl_xor(pB0, m);  pB1 += __shfl_xor(pB1, m);  pB2 += __shfl_xor(pB2, m);
    }
    if (tid < BT * 3) ((float*)red)[tid] = 0.f;
    __syncthreads();
    if (lane < 4) {   // one partial per wave per batch
        atomicAdd(&red[lane][0], pA0);
        atomicAdd(&red[lane][1], pA1);
        atomicAdd(&red[lane][2], pA2);
        atomicAdd(&red[4 + lane][0], pB0);
        atomicAdd(&red[4 + lane][1], pB1);
        atomicAdd(&red[4 + lane][2], pB2);
    }
    __syncthreads();
    if (tid < BT) {
        const float l0 = red[tid][0] + b_lin[0];
        const float l1 = red[tid][1] + b_lin[1];
        const float l2 = red[tid][2] + b_lin[2];
        const float m  = fmaxf(l0, fmaxf(l1, l2));
        const float sm = __expf(l0 - m) + __expf(l1 - m) + __expf(l2 - m);
        const float ls = __logf(sm);
        out[(b0 + tid) * 3 + 0] = l0 - m - ls;
        out[(b0 + tid) * 3 + 1] = l1 - m - ls;
        out[(b0 + tid) * 3 + 2] = l2 - m - ls;
    }
}

extern "C" void kernel_launch(void* const* d_in, const int* in_sizes, int n_in,
                              void* d_out, int out_size, void* d_ws, size_t ws_size,
                              hipStream_t stream) {
    const float* x     = (const float*)d_in[0];
    const float* W_ih  = (const float*)d_in[1];
    const float* W_hh  = (const float*)d_in[2];
    const float* b_ih  = (const float*)d_in[3];
    const float* b_hh  = (const float*)d_in[4];
    const float* W_lin = (const float*)d_in[5];
    const float* b_lin = (const float*)d_in[6];
    float* out = (float*)d_out;

    const int B = in_sizes[0] / T_LEN;   // 2048
    lstm_mfma_kernel<<<B / BT, 256, 0, stream>>>(x, W_ih, W_hh, b_ih, b_hh,
                                                 W_lin, b_lin, out);
}

// Round 8
// 528.931 us; speedup vs baseline: 1.6636x; 1.6636x over previous
//
#include <hip/hip_runtime.h>
#include <hip/hip_bf16.h>

#define T_LEN 2048
#define HDIM  64
#define BT    4            // batches per block -> 512 blocks = 2 blocks/CU
#define XS    (T_LEN + 4)  // x row stride (floats)
#define HS    72           // h_lds row stride in bf16
#define L2E   1.4426950408889634f   // log2(e)
#define L2E2  2.8853900817779268f   // 2*log2(e)

typedef __attribute__((ext_vector_type(8))) short bf16x8;
typedef __attribute__((ext_vector_type(4))) float f32x4;

__device__ __forceinline__ float rcp_f(float x)  { return __builtin_amdgcn_rcpf(x); }
__device__ __forceinline__ float exp2_f(float x) { return __builtin_amdgcn_exp2f(x); }
__device__ __forceinline__ unsigned short f2bf(float f) {
    unsigned int u = __float_as_uint(f);
    u += 0x7fffu + ((u >> 16) & 1u);
    return (unsigned short)(u >> 16);
}

// Round-6 structure (BT=4, 512 blocks = 2 independent blocks/CU; wave w owns
// 16 hidden units; 16 MFMA cols = 4 batches x 4 row-selects; each lane = one
// (unit,batch) pair; weights prescaled into exp2 domain). Round-8 diet:
//  - zero-quad C-in: persistent {0,0,0,0} as MFMA C (D != C); bias+wih*x is
//    added AFTER the reg-select -> no 16-mov splat, MFMAs start right after
//    the h ds_read.
//  - fused-rcp nonlinearities: i*g = (e2-1)*rcp((1+e0)(e2+1)) and
//    o*tanh(c) = (eC-1)*rcp((1+e3)(eC+1)), c clamped at 32 (tanh(32)==1 in
//    fp32) so exp2 can't reach inf and produce inf*0 NaN. 10 -> 8 trans/step.
// (Round 7 showed 1 block/CU static interleave loses to 2-block overlap.)
__global__ __launch_bounds__(256, 2) void lstm_mfma_kernel(
    const float* __restrict__ x,      // [B, T, 1]
    const float* __restrict__ W_ih,   // [4H, 1]
    const float* __restrict__ W_hh,   // [4H, H]
    const float* __restrict__ b_ih,   // [4H]
    const float* __restrict__ b_hh,   // [4H]
    const float* __restrict__ W_lin,  // [3, H]
    const float* __restrict__ b_lin,  // [3]
    float* __restrict__ out)          // [B, 3]
{
    const int tid  = threadIdx.x;
    const int lane = tid & 63;
    const int wv   = tid >> 6;       // wave 0..3
    const int col  = lane & 15;
    const int hi   = lane >> 4;      // k/row subgroup
    const int bq   = col & 3;        // batch serviced by this lane
    const int s    = col >> 2;       // C/D reg select: row = hi*4 + s
    const int b0   = blockIdx.x * BT;

    __shared__ float sx[BT][XS];
    __shared__ short hl[2][BT][HS];
    __shared__ float red[BT][3];

    for (int i = tid; i < 2 * BT * HS; i += 256) ((short*)hl)[i] = 0;

    // ---- stage all T for the 4 batches (coalesced float4) ----
    #pragma unroll
    for (int q = 0; q < 8; ++q) {
        const int idx = q * 256 + tid;
        const int row = idx >> 9;
        const int c4  = idx & 511;
        *(float4*)&sx[row][c4 * 4] =
            ((const float4*)(x + (size_t)(b0 + row) * T_LEN))[c4];
    }

    // ---- resident W_hh A-fragments (bf16), prescaled into exp2 domain ----
    const float scl[4] = {L2E, L2E, L2E2, L2E};   // i,f sigmoid; g tanh(2x); o sigmoid
    bf16x8 wf[4][2];
    #pragma unroll
    for (int g = 0; g < 4; ++g) {
        const int rowA = 64 * g + 16 * wv + col;
        #pragma unroll
        for (int kc = 0; kc < 2; ++kc) {
            const float* p = W_hh + rowA * HDIM + kc * 32 + hi * 8;
            bf16x8 f;
            #pragma unroll
            for (int j = 0; j < 8; ++j) f[j] = (short)f2bf(p[j] * scl[g]);
            wf[g][kc] = f;
        }
    }
    float wih1[4], bias1[4];
    #pragma unroll
    for (int g = 0; g < 4; ++g) {
        const int row = 64 * g + 16 * wv + hi * 4 + s;
        wih1[g]  = W_ih[row] * scl[g];
        bias1[g] = (b_ih[row] + b_hh[row]) * scl[g];
    }

    float cst = 0.f, hf = 0.f;
    const int sb0 = s & 1, sb1 = s >> 1;
    const int hwr = 16 * wv + hi * 4 + s;
    const int hi8 = hi * 8;

    const f32x4 zq = {0.f, 0.f, 0.f, 0.f};   // persistent MFMA C-in

    // static double-buffer pointers: zero per-step address arithmetic
    const short* hrd0 = &hl[0][bq][0];
    const short* hrd1 = &hl[1][bq][0];
    short* hwp1 = &hl[1][bq][hwr];
    short* hwp0 = &hl[0][bq][hwr];
    const float* xp = &sx[bq][0];

    __syncthreads();   // covers hl zero-init + sx staging

#define STEP(HRD, HWP, XV) do {                                               \
    const bf16x8 hb0 = *(const bf16x8*)((HRD) + hi8);                         \
    const bf16x8 hb1 = *(const bf16x8*)((HRD) + 32 + hi8);                    \
    f32x4 a0 = __builtin_amdgcn_mfma_f32_16x16x32_bf16(wf[0][0], hb0, zq, 0, 0, 0); \
    f32x4 a1 = __builtin_amdgcn_mfma_f32_16x16x32_bf16(wf[1][0], hb0, zq, 0, 0, 0); \
    f32x4 a2 = __builtin_amdgcn_mfma_f32_16x16x32_bf16(wf[2][0], hb0, zq, 0, 0, 0); \
    f32x4 a3 = __builtin_amdgcn_mfma_f32_16x16x32_bf16(wf[3][0], hb0, zq, 0, 0, 0); \
    a0 = __builtin_amdgcn_mfma_f32_16x16x32_bf16(wf[0][1], hb1, a0, 0, 0, 0); \
    a1 = __builtin_amdgcn_mfma_f32_16x16x32_bf16(wf[1][1], hb1, a1, 0, 0, 0); \
    a2 = __builtin_amdgcn_mfma_f32_16x16x32_bf16(wf[2][1], hb1, a2, 0, 0, 0); \
    a3 = __builtin_amdgcn_mfma_f32_16x16x32_bf16(wf[3][1], hb1, a3, 0, 0, 0); \
    const float g0 = (sb1 ? (sb0 ? a0[3] : a0[2]) : (sb0 ? a0[1] : a0[0]))    \
                     + (bias1[0] + wih1[0] * (XV));                           \
    const float g1 = (sb1 ? (sb0 ? a1[3] : a1[2]) : (sb0 ? a1[1] : a1[0]))    \
                     + (bias1[1] + wih1[1] * (XV));                           \
    const float g2 = (sb1 ? (sb0 ? a2[3] : a2[2]) : (sb0 ? a2[1] : a2[0]))    \
                     + (bias1[2] + wih1[2] * (XV));                           \
    const float g3 = (sb1 ? (sb0 ? a3[3] : a3[2]) : (sb0 ? a3[1] : a3[0]))    \
                     + (bias1[3] + wih1[3] * (XV));                           \
    const float e0 = exp2_f(-g0);                                             \
    const float e1 = exp2_f(-g1);                                             \
    const float e2 = exp2_f(g2);                                              \
    const float e3 = exp2_f(-g3);                                             \
    const float fv = rcp_f(1.0f + e1);                                        \
    const float ig = (e2 - 1.0f) * rcp_f((1.0f + e0) * (e2 + 1.0f));          \
    cst = fv * cst + ig;                                                      \
    const float cc = fminf(cst, 32.0f);    /* tanh(32)==1 in fp32; no inf */  \
    const float eC = exp2_f(L2E2 * cc);                                       \
    hf = (eC - 1.0f) * rcp_f((1.0f + e3) * (eC + 1.0f));                      \
    unsigned int rr;                                                          \
    asm("v_cvt_pk_bf16_f32 %0, %1, %1" : "=v"(rr) : "v"(hf));                 \
    *(HWP) = (short)rr;                                                       \
} while (0)

    for (int t = 0; t < T_LEN; t += 2) {
        const float2 xv2 = *(const float2*)(xp + t);   // one ds_read_b64
        STEP(hrd0, hwp1, xv2.x);
        __syncthreads();
        STEP(hrd1, hwp0, xv2.y);
        __syncthreads();
    }
#undef STEP

    // ---- epilogue: logits = W_lin @ h_T + b_lin, then log_softmax ----
    float p0 = W_lin[0 * HDIM + hwr] * hf;
    float p1 = W_lin[1 * HDIM + hwr] * hf;
    float p2 = W_lin[2 * HDIM + hwr] * hf;
    #pragma unroll
    for (int m = 4; m <= 32; m <<= 1) {
        p0 += __shfl_xor(p0, m);
        p1 += __shfl_xor(p1, m);
        p2 += __shfl_xor(p2, m);
    }
    if (tid < BT * 3) ((float*)red)[tid] = 0.f;
    __syncthreads();
    if (lane < 4) {
        atomicAdd(&red[lane][0], p0);
        atomicAdd(&red[lane][1], p1);
        atomicAdd(&red[lane][2], p2);
    }
    __syncthreads();
    if (tid < BT) {
        const float l0 = red[tid][0] + b_lin[0];
        const float l1 = red[tid][1] + b_lin[1];
        const float l2 = red[tid][2] + b_lin[2];
        const float m  = fmaxf(l0, fmaxf(l1, l2));
        const float sm = __expf(l0 - m) + __expf(l1 - m) + __expf(l2 - m);
        const float ls = __logf(sm);
        out[(b0 + tid) * 3 + 0] = l0 - m - ls;
        out[(b0 + tid) * 3 + 1] = l1 - m - ls;
        out[(b0 + tid) * 3 + 2] = l2 - m - ls;
    }
}

extern "C" void kernel_launch(void* const* d_in, const int* in_sizes, int n_in,
                              void* d_out, int out_size, void* d_ws, size_t ws_size,
                              hipStream_t stream) {
    const float* x     = (const float*)d_in[0];
    const float* W_ih  = (const float*)d_in[1];
    const float* W_hh  = (const float*)d_in[2];
    const float* b_ih  = (const float*)d_in[3];
    const float* b_hh  = (const float*)d_in[4];
    const float* W_lin = (const float*)d_in[5];
    const float* b_lin = (const float*)d_in[6];
    float* out = (float*)d_out;

    const int B = in_sizes[0] / T_LEN;   // 2048
    lstm_mfma_kernel<<<B / BT, 256, 0, stream>>>(x, W_ih, W_hh, b_ih, b_hh,
                                                 W_lin, b_lin, out);
}